// Round 1
// baseline (5544.061 us; speedup 1.0000x reference)
//
#include <hip/hip_runtime.h>

#define DD 256
#define NVAR 20000
#define NFAC 40000
#define NEDGE 320000
#define NGRAPH 64

#define BM 64
#define BN 64
#define BK 32

// C[M x 256] = (HASRES ? res : 0) + act( A1@W1 + (HASA2 ? A2@W2 : 0) + bias )
// A: M x 256 row-major. W slices: row-major with row stride 256.
template<bool RELU, bool HASA2, bool HASRES>
__global__ __launch_bounds__(256)
void gemm_k(const float* __restrict__ A1, const float* __restrict__ W1,
            const float* __restrict__ A2, const float* __restrict__ W2,
            const float* __restrict__ bias, const float* __restrict__ res,
            float* __restrict__ C, int M)
{
    __shared__ float sA[BK][BM + 4];
    __shared__ float sW[BK][BN + 4];
    const int tid = threadIdx.x;
    const int bm = blockIdx.x * BM;
    const int bn = blockIdx.y * BN;

    float acc[4][4];
#pragma unroll
    for (int i = 0; i < 4; ++i)
#pragma unroll
        for (int j = 0; j < 4; ++j) acc[i][j] = 0.f;

    const int m0 = (tid >> 4) * 4;   // 0..60
    const int n0 = (tid & 15) * 4;   // 0..60

    const int lam = tid >> 2;        // A-tile row 0..63
    const int lak = (tid & 3) * 8;   // A-tile col base (8 floats)
    const int lwk = tid >> 3;        // W-tile row 0..31
    const int lwn = (tid & 7) * 8;   // W-tile col base (8 floats)

    const int nops = HASA2 ? 2 : 1;
    for (int op = 0; op < nops; ++op) {
        const float* A = (op == 0) ? A1 : A2;
        const float* W = (op == 0) ? W1 : W2;
        for (int k0 = 0; k0 < DD; k0 += BK) {
            // ---- load A tile (64 rows x 32 cols), transposed into sA[k][m]
            {
                int row = bm + lam;
                float v[8];
                if (row < M) {
                    const float* src = A + (size_t)row * DD + k0 + lak;
                    float4 v0 = *(const float4*)(src);
                    float4 v1 = *(const float4*)(src + 4);
                    v[0]=v0.x; v[1]=v0.y; v[2]=v0.z; v[3]=v0.w;
                    v[4]=v1.x; v[5]=v1.y; v[6]=v1.z; v[7]=v1.w;
                } else {
#pragma unroll
                    for (int j = 0; j < 8; ++j) v[j] = 0.f;
                }
#pragma unroll
                for (int j = 0; j < 8; ++j) sA[lak + j][lam] = v[j];
            }
            // ---- load W tile (32 rows x 64 cols) into sW[k][n]
            {
                const float* src = W + (size_t)(k0 + lwk) * DD + bn + lwn;
                float4 v0 = *(const float4*)(src);
                float4 v1 = *(const float4*)(src + 4);
                *(float4*)&sW[lwk][lwn]     = v0;
                *(float4*)&sW[lwk][lwn + 4] = v1;
            }
            __syncthreads();
#pragma unroll
            for (int k = 0; k < BK; ++k) {
                float4 a = *(const float4*)&sA[k][m0];
                float4 w = *(const float4*)&sW[k][n0];
                float av[4] = {a.x, a.y, a.z, a.w};
                float wv[4] = {w.x, w.y, w.z, w.w};
#pragma unroll
                for (int i = 0; i < 4; ++i)
#pragma unroll
                    for (int j = 0; j < 4; ++j) acc[i][j] += av[i] * wv[j];
            }
            __syncthreads();
        }
    }

    // ---- epilogue
    float bvv[4] = {0.f, 0.f, 0.f, 0.f};
    if (bias) {
        float4 bv = *(const float4*)(bias + bn + n0);
        bvv[0]=bv.x; bvv[1]=bv.y; bvv[2]=bv.z; bvv[3]=bv.w;
    }
#pragma unroll
    for (int i = 0; i < 4; ++i) {
        int row = bm + m0 + i;
        if (row < M) {
            float ov[4];
#pragma unroll
            for (int j = 0; j < 4; ++j) {
                float v = acc[i][j] + bvv[j];
                if (RELU) v = fmaxf(v, 0.f);
                ov[j] = v;
            }
            if (HASRES) {
                float4 r = *(const float4*)(res + (size_t)row * DD + bn + n0);
                ov[0] += r.x; ov[1] += r.y; ov[2] += r.z; ov[3] += r.w;
            }
            float4 o = make_float4(ov[0], ov[1], ov[2], ov[3]);
            *(float4*)(C + (size_t)row * DD + bn + n0) = o;
        }
    }
}

// msg = relu(Pa[idxA[e]] + Pb[idxB[e]]); agg[idxA[e]] += msg   (bias folded into Pa)
__global__ __launch_bounds__(256)
void edge_k(const float* __restrict__ Pa, const float* __restrict__ Pb,
            const int* __restrict__ idxA, const int* __restrict__ idxB,
            float* __restrict__ agg)
{
    int e = blockIdx.x * 4 + (threadIdx.x >> 6);
    int lane = threadIdx.x & 63;
    int ia = idxA[e];
    int ib = idxB[e];
    const float4 a = *(const float4*)(Pa + (size_t)ia * DD + lane * 4);
    const float4 b = *(const float4*)(Pb + (size_t)ib * DD + lane * 4);
    float* dst = agg + (size_t)ia * DD + lane * 4;
    atomicAdd(dst + 0, fmaxf(a.x + b.x, 0.f));
    atomicAdd(dst + 1, fmaxf(a.y + b.y, 0.f));
    atomicAdd(dst + 2, fmaxf(a.z + b.z, 0.f));
    atomicAdd(dst + 3, fmaxf(a.w + b.w, 0.f));
}

// gate[f] = dot(fac[f], gw) + gb[0]    (one wave per factor)
__global__ __launch_bounds__(256)
void gate_k(const float* __restrict__ fac, const float* __restrict__ gw,
            const float* __restrict__ gb, float* __restrict__ gate)
{
    int f = blockIdx.x * 4 + (threadIdx.x >> 6);
    int lane = threadIdx.x & 63;
    float4 x = *(const float4*)(fac + (size_t)f * DD + lane * 4);
    float4 w = *(const float4*)(gw + lane * 4);
    float s = x.x * w.x + x.y * w.y + x.z * w.z + x.w * w.w;
#pragma unroll
    for (int o = 32; o > 0; o >>= 1) s += __shfl_down(s, o);
    if (lane == 0) gate[f] = s + gb[0];
}

// per-graph max and softmax denominator (block per graph; batch sorted but we scan all)
__global__ __launch_bounds__(256)
void segsm_k(const float* __restrict__ gate, const int* __restrict__ batch,
             float* __restrict__ mx, float* __restrict__ den)
{
    int g = blockIdx.x;
    int tid = threadIdx.x;
    __shared__ float red[256];
    float m = -1e30f;
    for (int i = tid; i < NFAC; i += 256)
        if (batch[i] == g) m = fmaxf(m, gate[i]);
    red[tid] = m; __syncthreads();
    for (int s = 128; s > 0; s >>= 1) {
        if (tid < s) red[tid] = fmaxf(red[tid], red[tid + s]);
        __syncthreads();
    }
    float gm = red[0]; __syncthreads();
    float sum = 0.f;
    for (int i = tid; i < NFAC; i += 256)
        if (batch[i] == g) sum += __expf(gate[i] - gm);
    red[tid] = sum; __syncthreads();
    for (int s = 128; s > 0; s >>= 1) {
        if (tid < s) red[tid] += red[tid + s];
        __syncthreads();
    }
    if (tid == 0) { mx[g] = gm; den[g] = red[0]; }
}

// gagg[b] += sum over factors of alpha_f * t[f]; block handles 64 consecutive factors,
// register-accumulates and flushes per graph-change (batch is sorted).
__global__ __launch_bounds__(256)
void gagg_k(const float* __restrict__ t, const float* __restrict__ gate,
            const int* __restrict__ batch, const float* __restrict__ mx,
            const float* __restrict__ den, float* __restrict__ gagg)
{
    int tid = threadIdx.x;
    int f0 = blockIdx.x * 64;
    float a = 0.f;
    int cur = batch[f0];
    for (int f = f0; f < f0 + 64; ++f) {
        int b = batch[f];
        if (b != cur) {
            atomicAdd(&gagg[(size_t)cur * DD + tid], a);
            a = 0.f; cur = b;
        }
        float coef = __expf(gate[f] - mx[b]) / den[b];
        a += coef * t[(size_t)f * DD + tid];
    }
    atomicAdd(&gagg[(size_t)cur * DD + tid], a);
}

// g = relu(gagg @ glW_top + glb)   (g_prev = 0 so bottom half of glW multiplies zeros)
__global__ __launch_bounds__(256)
void gfin_k(const float* __restrict__ gagg, const float* __restrict__ glW,
            const float* __restrict__ glb, float* __restrict__ gout)
{
    int row = blockIdx.x, col = threadIdx.x;
    float s = glb[col];
    for (int k = 0; k < DD; ++k) s += gagg[row * DD + k] * glW[k * DD + col];
    gout[row * DD + col] = fmaxf(s, 0.f);
}

extern "C" void kernel_launch(void* const* d_in, const int* in_sizes, int n_in,
                              void* d_out, int out_size, void* d_ws, size_t ws_size,
                              hipStream_t stream) {
    (void)in_sizes; (void)n_in; (void)out_size; (void)ws_size;
    const float* variables = (const float*)d_in[0];
    const float* factors   = (const float*)d_in[1];
    /* d_in[2] edge_attr unused */
    const int*   edge_index = (const int*)d_in[3];
    const int*   batch      = (const int*)d_in[4];
    const float* mW_v2f = (const float*)d_in[5];
    const float* mb_v2f = (const float*)d_in[6];
    const float* cW_v2f = (const float*)d_in[7];
    const float* cb_v2f = (const float*)d_in[8];
    const float* mW_f2v = (const float*)d_in[9];
    const float* mb_f2v = (const float*)d_in[10];
    const float* cW_f2v = (const float*)d_in[11];
    const float* cb_f2v = (const float*)d_in[12];
    const float* gate_W = (const float*)d_in[13];
    const float* gate_b = (const float*)d_in[14];
    const float* att_W  = (const float*)d_in[15];
    const float* att_b  = (const float*)d_in[16];
    const float* gl_W   = (const float*)d_in[17];
    const float* gl_b   = (const float*)d_in[18];

    const int* src = edge_index;           // row 0: variable idx
    const int* dst = edge_index + NEDGE;   // row 1: factor idx

    float* out = (float*)d_out;
    float* V1 = out;                        // NVAR*DD (d_out variable region as ping buffer)
    float* F1 = out + (size_t)NVAR * DD;    // NFAC*DD (d_out factor region)
    float* gout = out + (size_t)(NVAR + NFAC) * DD;

    float* ws  = (float*)d_ws;
    float* F0   = ws;                               // NFAC*DD
    float* aggF = F0 + (size_t)NFAC * DD;           // NFAC*DD
    float* V0   = aggF + (size_t)NFAC * DD;         // NVAR*DD
    float* aggV = V0 + (size_t)NVAR * DD;           // NVAR*DD
    float* gate = aggV + (size_t)NVAR * DD;         // NFAC
    float* mx   = gate + NFAC;                      // NGRAPH
    float* den  = mx + NGRAPH;                      // NGRAPH
    float* gagg = den + NGRAPH;                     // NGRAPH*DD

    // init current node states into d_out regions
    hipMemcpyAsync(V1, variables, (size_t)NVAR * DD * sizeof(float), hipMemcpyDeviceToDevice, stream);
    hipMemcpyAsync(F1, factors,   (size_t)NFAC * DD * sizeof(float), hipMemcpyDeviceToDevice, stream);

    float* fac = F1; float* ffree = F0;
    float* var = V1; float* vfree = V0;

    dim3 blk(256);
    dim3 gF((NFAC + BM - 1) / BM, DD / BN);
    dim3 gV((NVAR + BM - 1) / BM, DD / BN);

    for (int l = 0; l < 2; ++l) {
        const float* mW = mW_v2f + (size_t)l * 2 * DD * DD;
        const float* mb = mb_v2f + (size_t)l * DD;
        const float* cW = cW_v2f + (size_t)l * 2 * DD * DD;
        const float* cb = cb_v2f + (size_t)l * DD;
        const float* fW = mW_f2v + (size_t)l * 2 * DD * DD;
        const float* fb = mb_f2v + (size_t)l * DD;
        const float* dW = cW_f2v + (size_t)l * 2 * DD * DD;
        const float* db = cb_f2v + (size_t)l * DD;

        // ---- variable -> factor
        // Pf = fac @ mW[:D] + mb  -> ffree ; Pv = var @ mW[D:] -> vfree
        gemm_k<false,false,false><<<gF, blk, 0, stream>>>(fac, mW, nullptr, nullptr, mb, nullptr, ffree, NFAC);
        gemm_k<false,false,false><<<gV, blk, 0, stream>>>(var, mW + DD * DD, nullptr, nullptr, nullptr, nullptr, vfree, NVAR);
        hipMemsetAsync(aggF, 0, (size_t)NFAC * DD * sizeof(float), stream);
        edge_k<<<dim3(NEDGE / 4), blk, 0, stream>>>(ffree, vfree, dst, src, aggF);
        // fac_new = relu(fac@cW[:D] + aggF@cW[D:] + cb) -> ffree
        gemm_k<true,true,false><<<gF, blk, 0, stream>>>(fac, cW, aggF, cW + DD * DD, cb, nullptr, ffree, NFAC);
        { float* t = fac; fac = ffree; ffree = t; }

        // ---- factor -> variable
        // Pv = var @ fW[:D] + fb -> vfree ; Pf = fac @ fW[D:] -> ffree
        gemm_k<false,false,false><<<gV, blk, 0, stream>>>(var, fW, nullptr, nullptr, fb, nullptr, vfree, NVAR);
        gemm_k<false,false,false><<<gF, blk, 0, stream>>>(fac, fW + DD * DD, nullptr, nullptr, nullptr, nullptr, ffree, NFAC);
        hipMemsetAsync(aggV, 0, (size_t)NVAR * DD * sizeof(float), stream);
        edge_k<<<dim3(NEDGE / 4), blk, 0, stream>>>(vfree, ffree, src, dst, aggV);
        // var_new = var + relu(var@dW[:D] + aggV@dW[D:] + db) -> vfree
        gemm_k<true,true,true><<<gV, blk, 0, stream>>>(var, dW, aggV, dW + DD * DD, db, var, vfree, NVAR);
        { float* t = var; var = vfree; vfree = t; }
    }
    // after 2 layers: fac == F1 (d_out factor region), var == V1 (d_out variable region)

    // ---- global node
    gate_k<<<dim3(NFAC / 4), blk, 0, stream>>>(fac, gate_W, gate_b, gate);
    segsm_k<<<dim3(NGRAPH), blk, 0, stream>>>(gate, batch, mx, den);
    // t = fac @ att_W + att_b -> ffree (F0)
    gemm_k<false,false,false><<<gF, blk, 0, stream>>>(fac, att_W, nullptr, nullptr, att_b, nullptr, ffree, NFAC);
    hipMemsetAsync(gagg, 0, (size_t)NGRAPH * DD * sizeof(float), stream);
    gagg_k<<<dim3(NFAC / 64), blk, 0, stream>>>(ffree, gate, batch, mx, den, gagg);
    gfin_k<<<dim3(NGRAPH), blk, 0, stream>>>(gagg, gl_W, gl_b, gout);
}

// Round 2
// 1668.403 us; speedup vs baseline: 3.3230x; 3.3230x over previous
//
#include <hip/hip_runtime.h>

#define DD 256
#define NVAR 20000
#define NFAC 40000
#define NEDGE 320000
#define NGRAPH 64

#define BM 64
#define BN 64
#define BK 32

// C[M x 256] = (HASRES ? res : 0) + act( A1@W1 + (HASA2 ? A2@W2 : 0) + bias )
template<bool RELU, bool HASA2, bool HASRES>
__global__ __launch_bounds__(256)
void gemm_k(const float* __restrict__ A1, const float* __restrict__ W1,
            const float* __restrict__ A2, const float* __restrict__ W2,
            const float* __restrict__ bias, const float* __restrict__ res,
            float* __restrict__ C, int M)
{
    __shared__ float sA[BK][BM + 4];
    __shared__ float sW[BK][BN + 4];
    const int tid = threadIdx.x;
    const int bm = blockIdx.x * BM;
    const int bn = blockIdx.y * BN;

    float acc[4][4];
#pragma unroll
    for (int i = 0; i < 4; ++i)
#pragma unroll
        for (int j = 0; j < 4; ++j) acc[i][j] = 0.f;

    const int m0 = (tid >> 4) * 4;
    const int n0 = (tid & 15) * 4;

    const int lam = tid >> 2;
    const int lak = (tid & 3) * 8;
    const int lwk = tid >> 3;
    const int lwn = (tid & 7) * 8;

    const int nops = HASA2 ? 2 : 1;
    for (int op = 0; op < nops; ++op) {
        const float* A = (op == 0) ? A1 : A2;
        const float* W = (op == 0) ? W1 : W2;
        for (int k0 = 0; k0 < DD; k0 += BK) {
            {
                int row = bm + lam;
                float v[8];
                if (row < M) {
                    const float* src = A + (size_t)row * DD + k0 + lak;
                    float4 v0 = *(const float4*)(src);
                    float4 v1 = *(const float4*)(src + 4);
                    v[0]=v0.x; v[1]=v0.y; v[2]=v0.z; v[3]=v0.w;
                    v[4]=v1.x; v[5]=v1.y; v[6]=v1.z; v[7]=v1.w;
                } else {
#pragma unroll
                    for (int j = 0; j < 8; ++j) v[j] = 0.f;
                }
#pragma unroll
                for (int j = 0; j < 8; ++j) sA[lak + j][lam] = v[j];
            }
            {
                const float* src = W + (size_t)(k0 + lwk) * DD + bn + lwn;
                float4 v0 = *(const float4*)(src);
                float4 v1 = *(const float4*)(src + 4);
                *(float4*)&sW[lwk][lwn]     = v0;
                *(float4*)&sW[lwk][lwn + 4] = v1;
            }
            __syncthreads();
#pragma unroll
            for (int k = 0; k < BK; ++k) {
                float4 a = *(const float4*)&sA[k][m0];
                float4 w = *(const float4*)&sW[k][n0];
                float av[4] = {a.x, a.y, a.z, a.w};
                float wv[4] = {w.x, w.y, w.z, w.w};
#pragma unroll
                for (int i = 0; i < 4; ++i)
#pragma unroll
                    for (int j = 0; j < 4; ++j) acc[i][j] += av[i] * wv[j];
            }
            __syncthreads();
        }
    }

    float bvv[4] = {0.f, 0.f, 0.f, 0.f};
    if (bias) {
        float4 bv = *(const float4*)(bias + bn + n0);
        bvv[0]=bv.x; bvv[1]=bv.y; bvv[2]=bv.z; bvv[3]=bv.w;
    }
#pragma unroll
    for (int i = 0; i < 4; ++i) {
        int row = bm + m0 + i;
        if (row < M) {
            float ov[4];
#pragma unroll
            for (int j = 0; j < 4; ++j) {
                float v = acc[i][j] + bvv[j];
                if (RELU) v = fmaxf(v, 0.f);
                ov[j] = v;
            }
            if (HASRES) {
                float4 r = *(const float4*)(res + (size_t)row * DD + bn + n0);
                ov[0] += r.x; ov[1] += r.y; ov[2] += r.z; ov[3] += r.w;
            }
            *(float4*)(C + (size_t)row * DD + bn + n0) = make_float4(ov[0], ov[1], ov[2], ov[3]);
        }
    }
}

// ---------------- CSR build ----------------
// count degrees for both partitions in one pass
__global__ __launch_bounds__(256)
void count_k(const int* __restrict__ src, const int* __restrict__ dst,
             int* __restrict__ cntV, int* __restrict__ cntF)
{
    int e = blockIdx.x * 256 + threadIdx.x;
    if (e < NEDGE) {
        atomicAdd(&cntF[dst[e]], 1);
        atomicAdd(&cntV[src[e]], 1);
    }
}

// single-block exclusive scan: offs[0..n] and a scatter cursor copy
__global__ __launch_bounds__(1024)
void scan_k(const int* __restrict__ cnt, int* __restrict__ offs,
            int* __restrict__ cur, int n)
{
    __shared__ int part[1024];
    const int t = threadIdx.x;
    const int chunk = (n + 1023) / 1024;
    const int lo = t * chunk;
    const int hi = (lo + chunk < n) ? lo + chunk : n;
    int s = 0;
    for (int i = lo; i < hi; ++i) s += cnt[i];
    part[t] = s;
    __syncthreads();
    for (int off = 1; off < 1024; off <<= 1) {
        int v = (t >= off) ? part[t - off] : 0;
        __syncthreads();
        part[t] += v;
        __syncthreads();
    }
    int run = (t == 0) ? 0 : part[t - 1];
    for (int i = lo; i < hi; ++i) {
        offs[i] = run; cur[i] = run;
        run += cnt[i];
    }
    if (hi == n && lo < n) offs[n] = run;
}

// scatter the opposite endpoint into CSR order for both partitions
__global__ __launch_bounds__(256)
void scatter_k(const int* __restrict__ src, const int* __restrict__ dst,
               int* __restrict__ curV, int* __restrict__ curF,
               int* __restrict__ lstV, int* __restrict__ lstF)
{
    int e = blockIdx.x * 256 + threadIdx.x;
    if (e < NEDGE) {
        int s = src[e], d = dst[e];
        int pf = atomicAdd(&curF[d], 1);
        lstF[pf] = s;
        int pv = atomicAdd(&curV[s], 1);
        lstV[pv] = d;
    }
}

// ---------------- gather-aggregate ----------------
// agg[a] = sum_{e in CSR(a)} relu(Pa[a] + Pb[lst[e]])    (one wave per node a)
__global__ __launch_bounds__(256)
void agg_k(const float* __restrict__ Pa, const float* __restrict__ Pb,
           const int* __restrict__ offs, const int* __restrict__ lst,
           float* __restrict__ agg, int Na)
{
    int a = blockIdx.x * 4 + (threadIdx.x >> 6);
    if (a >= Na) return;
    int lane = threadIdx.x & 63;
    const size_t c = (size_t)lane * 4;
    float4 base = *(const float4*)(Pa + (size_t)a * DD + c);
    float4 s = make_float4(0.f, 0.f, 0.f, 0.f);
    int e0 = offs[a], e1 = offs[a + 1];
    for (int e = e0; e < e1; ++e) {
        int b = lst[e];
        float4 x = *(const float4*)(Pb + (size_t)b * DD + c);
        s.x += fmaxf(base.x + x.x, 0.f);
        s.y += fmaxf(base.y + x.y, 0.f);
        s.z += fmaxf(base.z + x.z, 0.f);
        s.w += fmaxf(base.w + x.w, 0.f);
    }
    *(float4*)(agg + (size_t)a * DD + c) = s;
}

// ---------------- global node ----------------
__global__ __launch_bounds__(256)
void gate_k(const float* __restrict__ fac, const float* __restrict__ gw,
            const float* __restrict__ gb, float* __restrict__ gate)
{
    int f = blockIdx.x * 4 + (threadIdx.x >> 6);
    int lane = threadIdx.x & 63;
    float4 x = *(const float4*)(fac + (size_t)f * DD + lane * 4);
    float4 w = *(const float4*)(gw + lane * 4);
    float s = x.x * w.x + x.y * w.y + x.z * w.z + x.w * w.w;
#pragma unroll
    for (int o = 32; o > 0; o >>= 1) s += __shfl_down(s, o);
    if (lane == 0) gate[f] = s + gb[0];
}

__global__ __launch_bounds__(256)
void segsm_k(const float* __restrict__ gate, const int* __restrict__ batch,
             float* __restrict__ mx, float* __restrict__ den)
{
    int g = blockIdx.x;
    int tid = threadIdx.x;
    __shared__ float red[256];
    float m = -1e30f;
    for (int i = tid; i < NFAC; i += 256)
        if (batch[i] == g) m = fmaxf(m, gate[i]);
    red[tid] = m; __syncthreads();
    for (int s = 128; s > 0; s >>= 1) {
        if (tid < s) red[tid] = fmaxf(red[tid], red[tid + s]);
        __syncthreads();
    }
    float gm = red[0]; __syncthreads();
    float sum = 0.f;
    for (int i = tid; i < NFAC; i += 256)
        if (batch[i] == g) sum += __expf(gate[i] - gm);
    red[tid] = sum; __syncthreads();
    for (int s = 128; s > 0; s >>= 1) {
        if (tid < s) red[tid] += red[tid + s];
        __syncthreads();
    }
    if (tid == 0) { mx[g] = gm; den[g] = red[0]; }
}

__global__ __launch_bounds__(256)
void gagg_k(const float* __restrict__ t, const float* __restrict__ gate,
            const int* __restrict__ batch, const float* __restrict__ mx,
            const float* __restrict__ den, float* __restrict__ gagg)
{
    int tid = threadIdx.x;
    int f0 = blockIdx.x * 64;
    float a = 0.f;
    int cur = batch[f0];
    for (int f = f0; f < f0 + 64; ++f) {
        int b = batch[f];
        if (b != cur) {
            atomicAdd(&gagg[(size_t)cur * DD + tid], a);
            a = 0.f; cur = b;
        }
        float coef = __expf(gate[f] - mx[b]) / den[b];
        a += coef * t[(size_t)f * DD + tid];
    }
    atomicAdd(&gagg[(size_t)cur * DD + tid], a);
}

__global__ __launch_bounds__(256)
void gfin_k(const float* __restrict__ gagg, const float* __restrict__ glW,
            const float* __restrict__ glb, float* __restrict__ gout)
{
    int row = blockIdx.x, col = threadIdx.x;
    float s = glb[col];
    for (int k = 0; k < DD; ++k) s += gagg[row * DD + k] * glW[k * DD + col];
    gout[row * DD + col] = fmaxf(s, 0.f);
}

extern "C" void kernel_launch(void* const* d_in, const int* in_sizes, int n_in,
                              void* d_out, int out_size, void* d_ws, size_t ws_size,
                              hipStream_t stream) {
    (void)in_sizes; (void)n_in; (void)out_size; (void)ws_size;
    const float* variables = (const float*)d_in[0];
    const float* factors   = (const float*)d_in[1];
    const int*   edge_index = (const int*)d_in[3];
    const int*   batch      = (const int*)d_in[4];
    const float* mW_v2f = (const float*)d_in[5];
    const float* mb_v2f = (const float*)d_in[6];
    const float* cW_v2f = (const float*)d_in[7];
    const float* cb_v2f = (const float*)d_in[8];
    const float* mW_f2v = (const float*)d_in[9];
    const float* mb_f2v = (const float*)d_in[10];
    const float* cW_f2v = (const float*)d_in[11];
    const float* cb_f2v = (const float*)d_in[12];
    const float* gate_W = (const float*)d_in[13];
    const float* gate_b = (const float*)d_in[14];
    const float* att_W  = (const float*)d_in[15];
    const float* att_b  = (const float*)d_in[16];
    const float* gl_W   = (const float*)d_in[17];
    const float* gl_b   = (const float*)d_in[18];

    const int* src = edge_index;           // row 0: variable idx
    const int* dst = edge_index + NEDGE;   // row 1: factor idx

    float* out = (float*)d_out;
    float* V1 = out;
    float* F1 = out + (size_t)NVAR * DD;
    float* gout = out + (size_t)(NVAR + NFAC) * DD;

    float* ws  = (float*)d_ws;
    float* F0   = ws;                               // NFAC*DD
    float* AGG  = F0 + (size_t)NFAC * DD;           // NFAC*DD (shared by both directions)
    float* V0   = AGG + (size_t)NFAC * DD;          // NVAR*DD
    float* gate = V0 + (size_t)NVAR * DD;           // NFAC
    float* mx   = gate + NFAC;                      // NGRAPH
    float* den  = mx + NGRAPH;                      // NGRAPH
    float* gagg = den + NGRAPH;                     // NGRAPH*DD
    int* ip    = (int*)(gagg + (size_t)NGRAPH * DD);
    int* cntF  = ip;              ip += NFAC;
    int* offsF = ip;              ip += NFAC + 1;
    int* curF  = ip;              ip += NFAC;
    int* lstF  = ip;              ip += NEDGE;
    int* cntV  = ip;              ip += NVAR;
    int* offsV = ip;              ip += NVAR + 1;
    int* curV  = ip;              ip += NVAR;
    int* lstV  = ip;              ip += NEDGE;

    // node-state ping buffers (final state must land in d_out regions)
    hipMemcpyAsync(V1, variables, (size_t)NVAR * DD * sizeof(float), hipMemcpyDeviceToDevice, stream);
    hipMemcpyAsync(F1, factors,   (size_t)NFAC * DD * sizeof(float), hipMemcpyDeviceToDevice, stream);

    // ---- build CSR for both partitions (once per launch)
    hipMemsetAsync(cntF, 0, NFAC * sizeof(int), stream);
    hipMemsetAsync(cntV, 0, NVAR * sizeof(int), stream);
    count_k<<<dim3((NEDGE + 255) / 256), dim3(256), 0, stream>>>(src, dst, cntV, cntF);
    scan_k<<<dim3(1), dim3(1024), 0, stream>>>(cntF, offsF, curF, NFAC);
    scan_k<<<dim3(1), dim3(1024), 0, stream>>>(cntV, offsV, curV, NVAR);
    scatter_k<<<dim3((NEDGE + 255) / 256), dim3(256), 0, stream>>>(src, dst, curV, curF, lstV, lstF);

    float* fac = F1; float* ffree = F0;
    float* var = V1; float* vfree = V0;

    dim3 blk(256);
    dim3 gF((NFAC + BM - 1) / BM, DD / BN);
    dim3 gV((NVAR + BM - 1) / BM, DD / BN);

    for (int l = 0; l < 2; ++l) {
        const float* mW = mW_v2f + (size_t)l * 2 * DD * DD;
        const float* mb = mb_v2f + (size_t)l * DD;
        const float* cW = cW_v2f + (size_t)l * 2 * DD * DD;
        const float* cb = cb_v2f + (size_t)l * DD;
        const float* fW = mW_f2v + (size_t)l * 2 * DD * DD;
        const float* fb = mb_f2v + (size_t)l * DD;
        const float* dW = cW_f2v + (size_t)l * 2 * DD * DD;
        const float* db = cb_f2v + (size_t)l * DD;

        // ---- variable -> factor
        gemm_k<false,false,false><<<gF, blk, 0, stream>>>(fac, mW, nullptr, nullptr, mb, nullptr, ffree, NFAC);
        gemm_k<false,false,false><<<gV, blk, 0, stream>>>(var, mW + DD * DD, nullptr, nullptr, nullptr, nullptr, vfree, NVAR);
        agg_k<<<dim3(NFAC / 4), blk, 0, stream>>>(ffree, vfree, offsF, lstF, AGG, NFAC);
        gemm_k<true,true,false><<<gF, blk, 0, stream>>>(fac, cW, AGG, cW + DD * DD, cb, nullptr, ffree, NFAC);
        { float* t = fac; fac = ffree; ffree = t; }

        // ---- factor -> variable
        gemm_k<false,false,false><<<gV, blk, 0, stream>>>(var, fW, nullptr, nullptr, fb, nullptr, vfree, NVAR);
        gemm_k<false,false,false><<<gF, blk, 0, stream>>>(fac, fW + DD * DD, nullptr, nullptr, nullptr, nullptr, ffree, NFAC);
        agg_k<<<dim3(NVAR / 4), blk, 0, stream>>>(vfree, ffree, offsV, lstV, AGG, NVAR);
        gemm_k<true,true,true><<<gV, blk, 0, stream>>>(var, dW, AGG, dW + DD * DD, db, var, vfree, NVAR);
        { float* t = var; var = vfree; vfree = t; }
    }

    // ---- global node
    gate_k<<<dim3(NFAC / 4), blk, 0, stream>>>(fac, gate_W, gate_b, gate);
    segsm_k<<<dim3(NGRAPH), blk, 0, stream>>>(gate, batch, mx, den);
    gemm_k<false,false,false><<<gF, blk, 0, stream>>>(fac, att_W, nullptr, nullptr, att_b, nullptr, ffree, NFAC);
    hipMemsetAsync(gagg, 0, (size_t)NGRAPH * DD * sizeof(float), stream);
    gagg_k<<<dim3(NFAC / 64), blk, 0, stream>>>(ffree, gate, batch, mx, den, gagg);
    gfin_k<<<dim3(NGRAPH), blk, 0, stream>>>(gagg, gl_W, gl_b, gout);
}

// Round 3
// 1088.959 us; speedup vs baseline: 5.0912x; 1.5321x over previous
//
#include <hip/hip_runtime.h>

#define DD 256
#define NVAR 20000
#define NFAC 40000
#define NEDGE 320000
#define NGRAPH 64

typedef __bf16 bf16_t;
typedef bf16_t bf16x8 __attribute__((ext_vector_type(8)));
typedef float f32x4 __attribute__((ext_vector_type(4)));

#define GBM 128
#define GBN 128
#define GBK 32
#define LDK 40   // padded k-stride (bf16 elems) for LDS tiles

// ---------------- MFMA GEMM ----------------
// C[M x 256] = (HASRES ? res : 0) + act( A1@W(kOff1) + (HASA2 ? A2@W(kOff2) : 0) + bias )
// A*: M x 256 f32 row-major. Wt: 256 x wtStride bf16, Wt[n][k] = W[k][n].
template<bool RELU, bool HASA2, bool HASRES>
__global__ __launch_bounds__(256)
void mgemm_k(const float* __restrict__ A1, const float* __restrict__ A2,
             const bf16_t* __restrict__ Wt, int wtStride, int kOff1, int kOff2,
             const float* __restrict__ bias, const float* __restrict__ res,
             float* __restrict__ C, int M)
{
    __shared__ bf16_t sA[GBM * LDK];
    __shared__ bf16_t sB[GBN * LDK];

    const int tid = threadIdx.x;
    const int bm = blockIdx.x * GBM;
    const int bn = blockIdx.y * GBN;

    const int w  = tid >> 6;           // wave 0..3
    const int l  = tid & 63;
    const int wr = w >> 1;             // wave row 0..1  (64-row band)
    const int wc = w & 1;              // wave col 0..1  (64-col band)
    const int lm = l & 15;
    const int kg = l >> 4;             // 0..3

    const int srow = tid >> 1;         // staging row / n  0..127
    const int shalf = (tid & 1) * 16;  // staging k offset 0 or 16

    f32x4 acc[4][4];
#pragma unroll
    for (int i = 0; i < 4; ++i)
#pragma unroll
        for (int j = 0; j < 4; ++j) acc[i][j] = (f32x4)0.f;

    const int nops = HASA2 ? 2 : 1;
    for (int op = 0; op < nops; ++op) {
        const float* Aop = (op == 0) ? A1 : A2;
        const int kOff = (op == 0) ? kOff1 : kOff2;
        for (int k0 = 0; k0 < DD; k0 += GBK) {
            // ---- stage A: 128 rows x 32 k, f32 -> bf16
            {
                bf16_t tmp[16];
                int grow = bm + srow;
                if (grow < M) {
                    const float4* p = (const float4*)(Aop + (size_t)grow * DD + k0 + shalf);
                    float4 x0 = p[0], x1 = p[1], x2 = p[2], x3 = p[3];
                    tmp[0]=(bf16_t)x0.x; tmp[1]=(bf16_t)x0.y; tmp[2]=(bf16_t)x0.z; tmp[3]=(bf16_t)x0.w;
                    tmp[4]=(bf16_t)x1.x; tmp[5]=(bf16_t)x1.y; tmp[6]=(bf16_t)x1.z; tmp[7]=(bf16_t)x1.w;
                    tmp[8]=(bf16_t)x2.x; tmp[9]=(bf16_t)x2.y; tmp[10]=(bf16_t)x2.z; tmp[11]=(bf16_t)x2.w;
                    tmp[12]=(bf16_t)x3.x; tmp[13]=(bf16_t)x3.y; tmp[14]=(bf16_t)x3.z; tmp[15]=(bf16_t)x3.w;
                } else {
#pragma unroll
                    for (int j = 0; j < 16; ++j) tmp[j] = (bf16_t)0.f;
                }
                bf16x8* d = (bf16x8*)&sA[srow * LDK + shalf];
                d[0] = *(bf16x8*)&tmp[0];
                d[1] = *(bf16x8*)&tmp[8];
            }
            // ---- stage B: 128 n-rows x 32 k from Wt (already bf16, k-contiguous)
            {
                const bf16x8* s = (const bf16x8*)(Wt + (size_t)(bn + srow) * wtStride + kOff + k0 + shalf);
                bf16x8* d = (bf16x8*)&sB[srow * LDK + shalf];
                d[0] = s[0];
                d[1] = s[1];
            }
            __syncthreads();
            // ---- MFMA
            bf16x8 af[4], bfr[4];
#pragma unroll
            for (int i = 0; i < 4; ++i)
                af[i] = *(bf16x8*)&sA[(wr * 64 + i * 16 + lm) * LDK + kg * 8];
#pragma unroll
            for (int j = 0; j < 4; ++j)
                bfr[j] = *(bf16x8*)&sB[(wc * 64 + j * 16 + lm) * LDK + kg * 8];
#pragma unroll
            for (int i = 0; i < 4; ++i)
#pragma unroll
                for (int j = 0; j < 4; ++j)
                    acc[i][j] = __builtin_amdgcn_mfma_f32_16x16x32_bf16(af[i], bfr[j], acc[i][j], 0, 0, 0);
            __syncthreads();
        }
    }

    // ---- epilogue: C row = bm + wr*64 + i*16 + kg*4 + r ; col = bn + wc*64 + j*16 + lm
#pragma unroll
    for (int j = 0; j < 4; ++j) {
        const int col = bn + wc * 64 + j * 16 + lm;
        const float bv = bias ? bias[col] : 0.f;
#pragma unroll
        for (int i = 0; i < 4; ++i) {
            const int rbase = bm + wr * 64 + i * 16 + kg * 4;
#pragma unroll
            for (int r = 0; r < 4; ++r) {
                const int rw = rbase + r;
                if (rw < M) {
                    float v = acc[i][j][r] + bv;
                    if (RELU) v = fmaxf(v, 0.f);
                    if (HASRES) v += res[(size_t)rw * DD + col];
                    C[(size_t)rw * DD + col] = v;
                }
            }
        }
    }
}

// ---------------- weight transpose: Wt[n][k] = (bf16)W[k][n] ----------------
__global__ __launch_bounds__(256)
void wt_k(const float* __restrict__ W, bf16_t* __restrict__ Wt, int KK)
{
    __shared__ float sh[32][33];
    const int k0 = blockIdx.x * 32, n0 = blockIdx.y * 32;
    const int tr = threadIdx.x >> 5, tc = threadIdx.x & 31;
#pragma unroll
    for (int it = 0; it < 4; ++it)
        sh[tr + 8 * it][tc] = W[(size_t)(k0 + tr + 8 * it) * DD + n0 + tc];
    __syncthreads();
#pragma unroll
    for (int it = 0; it < 4; ++it)
        Wt[(size_t)(n0 + tr + 8 * it) * KK + k0 + tc] = (bf16_t)sh[tc][tr + 8 * it];
}

// ---------------- CSR build ----------------
__global__ __launch_bounds__(256)
void count_k(const int* __restrict__ src, const int* __restrict__ dst,
             int* __restrict__ cntV, int* __restrict__ cntF)
{
    int e = blockIdx.x * 256 + threadIdx.x;
    if (e < NEDGE) {
        atomicAdd(&cntF[dst[e]], 1);
        atomicAdd(&cntV[src[e]], 1);
    }
}

__global__ __launch_bounds__(1024)
void scan_k(const int* __restrict__ cnt, int* __restrict__ offs,
            int* __restrict__ cur, int n)
{
    __shared__ int part[1024];
    const int t = threadIdx.x;
    const int chunk = (n + 1023) / 1024;
    const int lo = t * chunk;
    const int hi = (lo + chunk < n) ? lo + chunk : n;
    int s = 0;
    for (int i = lo; i < hi; ++i) s += cnt[i];
    part[t] = s;
    __syncthreads();
    for (int off = 1; off < 1024; off <<= 1) {
        int v = (t >= off) ? part[t - off] : 0;
        __syncthreads();
        part[t] += v;
        __syncthreads();
    }
    int run = (t == 0) ? 0 : part[t - 1];
    for (int i = lo; i < hi; ++i) {
        offs[i] = run; cur[i] = run;
        run += cnt[i];
    }
    if (hi == n && lo < n) offs[n] = run;
}

__global__ __launch_bounds__(256)
void scatter_k(const int* __restrict__ src, const int* __restrict__ dst,
               int* __restrict__ curV, int* __restrict__ curF,
               int* __restrict__ lstV, int* __restrict__ lstF)
{
    int e = blockIdx.x * 256 + threadIdx.x;
    if (e < NEDGE) {
        int s = src[e], d = dst[e];
        int pf = atomicAdd(&curF[d], 1);
        lstF[pf] = s;
        int pv = atomicAdd(&curV[s], 1);
        lstV[pv] = d;
    }
}

// ---------------- gather-aggregate ----------------
__global__ __launch_bounds__(256)
void agg_k(const float* __restrict__ Pa, const float* __restrict__ Pb,
           const int* __restrict__ offs, const int* __restrict__ lst,
           float* __restrict__ agg, int Na)
{
    int a = blockIdx.x * 4 + (threadIdx.x >> 6);
    if (a >= Na) return;
    int lane = threadIdx.x & 63;
    const size_t c = (size_t)lane * 4;
    float4 base = *(const float4*)(Pa + (size_t)a * DD + c);
    float4 s = make_float4(0.f, 0.f, 0.f, 0.f);
    int e0 = offs[a], e1 = offs[a + 1];
    for (int e = e0; e < e1; ++e) {
        int b = lst[e];
        float4 x = *(const float4*)(Pb + (size_t)b * DD + c);
        s.x += fmaxf(base.x + x.x, 0.f);
        s.y += fmaxf(base.y + x.y, 0.f);
        s.z += fmaxf(base.z + x.z, 0.f);
        s.w += fmaxf(base.w + x.w, 0.f);
    }
    *(float4*)(agg + (size_t)a * DD + c) = s;
}

// ---------------- global node ----------------
__global__ __launch_bounds__(256)
void gate_k(const float* __restrict__ fac, const float* __restrict__ gw,
            const float* __restrict__ gb, float* __restrict__ gate)
{
    int f = blockIdx.x * 4 + (threadIdx.x >> 6);
    int lane = threadIdx.x & 63;
    float4 x = *(const float4*)(fac + (size_t)f * DD + lane * 4);
    float4 w = *(const float4*)(gw + lane * 4);
    float s = x.x * w.x + x.y * w.y + x.z * w.z + x.w * w.w;
#pragma unroll
    for (int o = 32; o > 0; o >>= 1) s += __shfl_down(s, o);
    if (lane == 0) gate[f] = s + gb[0];
}

__global__ __launch_bounds__(256)
void segsm_k(const float* __restrict__ gate, const int* __restrict__ batch,
             float* __restrict__ mx, float* __restrict__ den)
{
    int g = blockIdx.x;
    int tid = threadIdx.x;
    __shared__ float red[256];
    float m = -1e30f;
    for (int i = tid; i < NFAC; i += 256)
        if (batch[i] == g) m = fmaxf(m, gate[i]);
    red[tid] = m; __syncthreads();
    for (int s = 128; s > 0; s >>= 1) {
        if (tid < s) red[tid] = fmaxf(red[tid], red[tid + s]);
        __syncthreads();
    }
    float gm = red[0]; __syncthreads();
    float sum = 0.f;
    for (int i = tid; i < NFAC; i += 256)
        if (batch[i] == g) sum += __expf(gate[i] - gm);
    red[tid] = sum; __syncthreads();
    for (int s = 128; s > 0; s >>= 1) {
        if (tid < s) red[tid] += red[tid + s];
        __syncthreads();
    }
    if (tid == 0) { mx[g] = gm; den[g] = red[0]; }
}

__global__ __launch_bounds__(256)
void gagg_k(const float* __restrict__ t, const float* __restrict__ gate,
            const int* __restrict__ batch, const float* __restrict__ mx,
            const float* __restrict__ den, float* __restrict__ gagg)
{
    int tid = threadIdx.x;
    int f0 = blockIdx.x * 64;
    float a = 0.f;
    int cur = batch[f0];
    for (int f = f0; f < f0 + 64; ++f) {
        int b = batch[f];
        if (b != cur) {
            atomicAdd(&gagg[(size_t)cur * DD + tid], a);
            a = 0.f; cur = b;
        }
        float coef = __expf(gate[f] - mx[b]) / den[b];
        a += coef * t[(size_t)f * DD + tid];
    }
    atomicAdd(&gagg[(size_t)cur * DD + tid], a);
}

__global__ __launch_bounds__(256)
void gfin_k(const float* __restrict__ gagg, const float* __restrict__ glW,
            const float* __restrict__ glb, float* __restrict__ gout)
{
    int row = blockIdx.x, col = threadIdx.x;
    float s = glb[col];
    for (int k = 0; k < DD; ++k) s += gagg[row * DD + k] * glW[k * DD + col];
    gout[row * DD + col] = fmaxf(s, 0.f);
}

extern "C" void kernel_launch(void* const* d_in, const int* in_sizes, int n_in,
                              void* d_out, int out_size, void* d_ws, size_t ws_size,
                              hipStream_t stream) {
    (void)in_sizes; (void)n_in; (void)out_size; (void)ws_size;
    const float* variables = (const float*)d_in[0];
    const float* factors   = (const float*)d_in[1];
    const int*   edge_index = (const int*)d_in[3];
    const int*   batch      = (const int*)d_in[4];
    const float* mW_v2f = (const float*)d_in[5];
    const float* mb_v2f = (const float*)d_in[6];
    const float* cW_v2f = (const float*)d_in[7];
    const float* cb_v2f = (const float*)d_in[8];
    const float* mW_f2v = (const float*)d_in[9];
    const float* mb_f2v = (const float*)d_in[10];
    const float* cW_f2v = (const float*)d_in[11];
    const float* cb_f2v = (const float*)d_in[12];
    const float* gate_W = (const float*)d_in[13];
    const float* gate_b = (const float*)d_in[14];
    const float* att_W  = (const float*)d_in[15];
    const float* att_b  = (const float*)d_in[16];
    const float* gl_W   = (const float*)d_in[17];
    const float* gl_b   = (const float*)d_in[18];

    const int* src = edge_index;           // row 0: variable idx
    const int* dst = edge_index + NEDGE;   // row 1: factor idx

    float* out = (float*)d_out;
    float* V1 = out;
    float* F1 = out + (size_t)NVAR * DD;
    float* gout = out + (size_t)(NVAR + NFAC) * DD;

    float* ws  = (float*)d_ws;
    float* F0   = ws;                               // NFAC*DD
    float* AGG  = F0 + (size_t)NFAC * DD;           // NFAC*DD
    float* V0   = AGG + (size_t)NFAC * DD;          // NVAR*DD
    float* gate = V0 + (size_t)NVAR * DD;           // NFAC
    float* mx   = gate + NFAC;                      // NGRAPH
    float* den  = mx + NGRAPH;                      // NGRAPH
    float* gagg = den + NGRAPH;                     // NGRAPH*DD
    int* ip    = (int*)(gagg + (size_t)NGRAPH * DD);
    int* cntF  = ip;              ip += NFAC;
    int* offsF = ip;              ip += NFAC + 1;
    int* curF  = ip;              ip += NFAC;
    int* lstF  = ip;              ip += NEDGE;
    int* cntV  = ip;              ip += NVAR;
    int* offsV = ip;              ip += NVAR + 1;
    int* curV  = ip;              ip += NVAR;
    int* lstV  = ip;              ip += NEDGE;
    // bf16 transposed-weight pool (16B aligned)
    bf16_t* wt = (bf16_t*)(((uintptr_t)ip + 15) & ~(uintptr_t)15);
    bf16_t* WT_mv2f[2]; bf16_t* WT_cv2f[2]; bf16_t* WT_mf2v[2]; bf16_t* WT_cf2v[2];
    size_t woff = 0;
    for (int l = 0; l < 2; ++l) { WT_mv2f[l] = wt + woff; woff += (size_t)DD * 2 * DD; }
    for (int l = 0; l < 2; ++l) { WT_cv2f[l] = wt + woff; woff += (size_t)DD * 2 * DD; }
    for (int l = 0; l < 2; ++l) { WT_mf2v[l] = wt + woff; woff += (size_t)DD * 2 * DD; }
    for (int l = 0; l < 2; ++l) { WT_cf2v[l] = wt + woff; woff += (size_t)DD * 2 * DD; }
    bf16_t* WT_att = wt + woff;

    dim3 blk(256);
    dim3 gT(2 * DD / 32, DD / 32);   // transpose grid for 512x256
    dim3 gTa(DD / 32, DD / 32);      // 256x256
    for (int l = 0; l < 2; ++l) {
        wt_k<<<gT, blk, 0, stream>>>(mW_v2f + (size_t)l * 2 * DD * DD, WT_mv2f[l], 2 * DD);
        wt_k<<<gT, blk, 0, stream>>>(cW_v2f + (size_t)l * 2 * DD * DD, WT_cv2f[l], 2 * DD);
        wt_k<<<gT, blk, 0, stream>>>(mW_f2v + (size_t)l * 2 * DD * DD, WT_mf2v[l], 2 * DD);
        wt_k<<<gT, blk, 0, stream>>>(cW_f2v + (size_t)l * 2 * DD * DD, WT_cf2v[l], 2 * DD);
    }
    wt_k<<<gTa, blk, 0, stream>>>(att_W, WT_att, DD);

    // node-state ping buffers (final state must land in d_out regions)
    hipMemcpyAsync(V1, variables, (size_t)NVAR * DD * sizeof(float), hipMemcpyDeviceToDevice, stream);
    hipMemcpyAsync(F1, factors,   (size_t)NFAC * DD * sizeof(float), hipMemcpyDeviceToDevice, stream);

    // ---- CSR build
    hipMemsetAsync(cntF, 0, NFAC * sizeof(int), stream);
    hipMemsetAsync(cntV, 0, NVAR * sizeof(int), stream);
    count_k<<<dim3((NEDGE + 255) / 256), blk, 0, stream>>>(src, dst, cntV, cntF);
    scan_k<<<dim3(1), dim3(1024), 0, stream>>>(cntF, offsF, curF, NFAC);
    scan_k<<<dim3(1), dim3(1024), 0, stream>>>(cntV, offsV, curV, NVAR);
    scatter_k<<<dim3((NEDGE + 255) / 256), blk, 0, stream>>>(src, dst, curV, curF, lstV, lstF);

    float* fac = F1; float* ffree = F0;
    float* var = V1; float* vfree = V0;

    dim3 gF2((NFAC + GBM - 1) / GBM, DD / GBN);
    dim3 gV2((NVAR + GBM - 1) / GBM, DD / GBN);

    for (int l = 0; l < 2; ++l) {
        const float* mb = mb_v2f + (size_t)l * DD;
        const float* cb = cb_v2f + (size_t)l * DD;
        const float* fb = mb_f2v + (size_t)l * DD;
        const float* db = cb_f2v + (size_t)l * DD;

        // ---- variable -> factor
        mgemm_k<false,false,false><<<gF2, blk, 0, stream>>>(fac, nullptr, WT_mv2f[l], 2*DD, 0, 0, mb, nullptr, ffree, NFAC);
        mgemm_k<false,false,false><<<gV2, blk, 0, stream>>>(var, nullptr, WT_mv2f[l], 2*DD, DD, 0, nullptr, nullptr, vfree, NVAR);
        agg_k<<<dim3(NFAC / 4), blk, 0, stream>>>(ffree, vfree, offsF, lstF, AGG, NFAC);
        mgemm_k<true,true,false><<<gF2, blk, 0, stream>>>(fac, AGG, WT_cv2f[l], 2*DD, 0, DD, cb, nullptr, ffree, NFAC);
        { float* t = fac; fac = ffree; ffree = t; }

        // ---- factor -> variable
        mgemm_k<false,false,false><<<gV2, blk, 0, stream>>>(var, nullptr, WT_mf2v[l], 2*DD, 0, 0, fb, nullptr, vfree, NVAR);
        mgemm_k<false,false,false><<<gF2, blk, 0, stream>>>(fac, nullptr, WT_mf2v[l], 2*DD, DD, 0, nullptr, nullptr, ffree, NFAC);
        agg_k<<<dim3(NVAR / 4), blk, 0, stream>>>(vfree, ffree, offsV, lstV, AGG, NVAR);
        mgemm_k<true,true,true><<<gV2, blk, 0, stream>>>(var, AGG, WT_cf2v[l], 2*DD, 0, DD, db, var, vfree, NVAR);
        { float* t = var; var = vfree; vfree = t; }
    }

    // ---- global node
    gate_k<<<dim3(NFAC / 4), blk, 0, stream>>>(fac, gate_W, gate_b, gate);
    segsm_k<<<dim3(NGRAPH), blk, 0, stream>>>(gate, batch, mx, den);
    mgemm_k<false,false,false><<<gF2, blk, 0, stream>>>(fac, nullptr, WT_att, DD, 0, 0, att_b, nullptr, ffree, NFAC);
    hipMemsetAsync(gagg, 0, (size_t)NGRAPH * DD * sizeof(float), stream);
    gagg_k<<<dim3(NFAC / 64), blk, 0, stream>>>(ffree, gate, batch, mx, den, gagg);
    gfin_k<<<dim3(NGRAPH), blk, 0, stream>>>(gagg, gl_W, gl_b, gout);
}

// Round 6
// 883.663 us; speedup vs baseline: 6.2740x; 1.2323x over previous
//
#include <hip/hip_runtime.h>

#define DD 256
#define NVAR 20000
#define NFAC 40000
#define NEDGE 320000
#define NGRAPH 64

#define NBF ((NFAC + 255) / 256)   // 157
#define NBV ((NVAR + 255) / 256)   // 79

typedef __bf16 bf16_t;
typedef bf16_t bf16x8 __attribute__((ext_vector_type(8)));
typedef bf16_t bf16x4 __attribute__((ext_vector_type(4)));
typedef float f32x4 __attribute__((ext_vector_type(4)));

#define GBM 128
#define GBN 128
#define GBK 32
#define LDK 40   // padded k-stride (bf16 elems) for LDS tiles

// ---------------- MFMA GEMM ----------------
// C[M x 256] = (HASRES ? res : 0) + act( A1@W(kOff1) + (HASA2 ? A2@W(kOff2) : 0) + bias )
// A1: M x 256 f32. A2: M x 256 (f32 or bf16 per A2BF). Wt[n][k] bf16, row stride wtStride.
// C: f32 or bf16 per OUTBF.
template<bool RELU, bool HASA2, bool HASRES, bool A2BF, bool OUTBF>
__global__ __launch_bounds__(256)
void mgemm_k(const float* __restrict__ A1, const void* __restrict__ A2v,
             const bf16_t* __restrict__ Wt, int wtStride, int kOff1, int kOff2,
             const float* __restrict__ bias, const float* __restrict__ res,
             void* __restrict__ Cv, int M)
{
    __shared__ bf16_t sA[GBM * LDK];
    __shared__ bf16_t sB[GBN * LDK];

    const int tid = threadIdx.x;
    const int bm = blockIdx.x * GBM;
    const int bn = blockIdx.y * GBN;

    const int w  = tid >> 6;
    const int l  = tid & 63;
    const int wr = w >> 1;
    const int wc = w & 1;
    const int lm = l & 15;
    const int kg = l >> 4;

    const int srow = tid >> 1;
    const int shalf = (tid & 1) * 16;

    f32x4 acc[4][4];
#pragma unroll
    for (int i = 0; i < 4; ++i)
#pragma unroll
        for (int j = 0; j < 4; ++j) acc[i][j] = (f32x4)0.f;

    const int nops = HASA2 ? 2 : 1;
    for (int op = 0; op < nops; ++op) {
        const int kOff = op ? kOff2 : kOff1;
        for (int k0 = 0; k0 < DD; k0 += GBK) {
            // ---- stage A tile (128 rows x 32 k)
            {
                const int grow = bm + srow;
                bf16x8* d = (bf16x8*)&sA[srow * LDK + shalf];
                if (op == 1 && A2BF) {
                    const bf16_t* A2b = (const bf16_t*)A2v;
                    if (grow < M) {
                        const bf16x8* s = (const bf16x8*)(A2b + (size_t)grow * DD + k0 + shalf);
                        d[0] = s[0]; d[1] = s[1];
                    } else {
                        d[0] = (bf16x8)(bf16_t)0.f; d[1] = (bf16x8)(bf16_t)0.f;
                    }
                } else {
                    const float* Aop = op ? (const float*)A2v : A1;
                    bf16_t tmp[16];
                    if (grow < M) {
                        const float4* p = (const float4*)(Aop + (size_t)grow * DD + k0 + shalf);
                        float4 x0 = p[0], x1 = p[1], x2 = p[2], x3 = p[3];
                        tmp[0]=(bf16_t)x0.x; tmp[1]=(bf16_t)x0.y; tmp[2]=(bf16_t)x0.z; tmp[3]=(bf16_t)x0.w;
                        tmp[4]=(bf16_t)x1.x; tmp[5]=(bf16_t)x1.y; tmp[6]=(bf16_t)x1.z; tmp[7]=(bf16_t)x1.w;
                        tmp[8]=(bf16_t)x2.x; tmp[9]=(bf16_t)x2.y; tmp[10]=(bf16_t)x2.z; tmp[11]=(bf16_t)x2.w;
                        tmp[12]=(bf16_t)x3.x; tmp[13]=(bf16_t)x3.y; tmp[14]=(bf16_t)x3.z; tmp[15]=(bf16_t)x3.w;
                    } else {
#pragma unroll
                        for (int j = 0; j < 16; ++j) tmp[j] = (bf16_t)0.f;
                    }
                    d[0] = *(bf16x8*)&tmp[0];
                    d[1] = *(bf16x8*)&tmp[8];
                }
            }
            // ---- stage B tile from Wt (bf16, k-contiguous)
            {
                const bf16x8* s = (const bf16x8*)(Wt + (size_t)(bn + srow) * wtStride + kOff + k0 + shalf);
                bf16x8* d = (bf16x8*)&sB[srow * LDK + shalf];
                d[0] = s[0];
                d[1] = s[1];
            }
            __syncthreads();
            bf16x8 af[4], bfr[4];
#pragma unroll
            for (int i = 0; i < 4; ++i)
                af[i] = *(bf16x8*)&sA[(wr * 64 + i * 16 + lm) * LDK + kg * 8];
#pragma unroll
            for (int j = 0; j < 4; ++j)
                bfr[j] = *(bf16x8*)&sB[(wc * 64 + j * 16 + lm) * LDK + kg * 8];
#pragma unroll
            for (int i = 0; i < 4; ++i)
#pragma unroll
                for (int j = 0; j < 4; ++j)
                    acc[i][j] = __builtin_amdgcn_mfma_f32_16x16x32_bf16(af[i], bfr[j], acc[i][j], 0, 0, 0);
            __syncthreads();
        }
    }

    // epilogue: row = bm + wr*64 + i*16 + kg*4 + r ; col = bn + wc*64 + j*16 + lm
#pragma unroll
    for (int j = 0; j < 4; ++j) {
        const int col = bn + wc * 64 + j * 16 + lm;
        const float bv = bias ? bias[col] : 0.f;
#pragma unroll
        for (int i = 0; i < 4; ++i) {
            const int rbase = bm + wr * 64 + i * 16 + kg * 4;
#pragma unroll
            for (int r = 0; r < 4; ++r) {
                const int rw = rbase + r;
                if (rw < M) {
                    float v = acc[i][j][r] + bv;
                    if (RELU) v = fmaxf(v, 0.f);
                    if (HASRES) v += res[(size_t)rw * DD + col];
                    if (OUTBF) ((bf16_t*)Cv)[(size_t)rw * DD + col] = (bf16_t)v;
                    else       ((float*)Cv)[(size_t)rw * DD + col] = v;
                }
            }
        }
    }
}

// ---------------- fused weight transposes: Wt[n][k] = (bf16)W[k][n] ----------------
struct WtJobs {
    const float* W[9];
    bf16_t* T[9];
    int KK[9];
};
__global__ __launch_bounds__(256)
void wtall_k(WtJobs jobs)
{
    __shared__ float sh[32][33];
    const int id = blockIdx.z;
    const float* W = jobs.W[id];
    bf16_t* Wt = jobs.T[id];
    const int KK = jobs.KK[id];
    const int k0 = blockIdx.x * 32, n0 = blockIdx.y * 32;
    if (k0 >= KK) return;
    const int tr = threadIdx.x >> 5, tc = threadIdx.x & 31;
#pragma unroll
    for (int it = 0; it < 4; ++it)
        sh[tr + 8 * it][tc] = W[(size_t)(k0 + tr + 8 * it) * DD + n0 + tc];
    __syncthreads();
#pragma unroll
    for (int it = 0; it < 4; ++it)
        Wt[(size_t)(n0 + tr + 8 * it) * KK + k0 + tc] = (bf16_t)sh[tc][tr + 8 * it];
}

// ---------------- CSR build ----------------
__global__ __launch_bounds__(256)
void count_k(const int* __restrict__ src, const int* __restrict__ dst,
             int* __restrict__ cntV, int* __restrict__ cntF)
{
    int e = blockIdx.x * 256 + threadIdx.x;
    if (e < NEDGE) {
        atomicAdd(&cntF[dst[e]], 1);
        atomicAdd(&cntV[src[e]], 1);
    }
}

// phase 1: per-block sums (both partitions in one grid)
__global__ __launch_bounds__(256)
void cs1_k(const int* __restrict__ cntF, const int* __restrict__ cntV,
           int* __restrict__ bsumF, int* __restrict__ bsumV)
{
    __shared__ int red[256];
    const int b = blockIdx.x;
    const int* cnt; int n; int* bsum; int bb;
    if (b < NBF) { cnt = cntF; n = NFAC; bsum = bsumF; bb = b; }
    else         { cnt = cntV; n = NVAR; bsum = bsumV; bb = b - NBF; }
    const int t = threadIdx.x;
    const int i = bb * 256 + t;
    red[t] = (i < n) ? cnt[i] : 0;
    __syncthreads();
    for (int s = 128; s > 0; s >>= 1) {
        if (t < s) red[t] += red[t + s];
        __syncthreads();
    }
    if (t == 0) bsum[bb] = red[0];
}

// phase 2: exclusive scan of block sums (block 0 -> F, block 1 -> V)
__global__ __launch_bounds__(256)
void cs2_k(int* __restrict__ bsumF, int* __restrict__ bsumV)
{
    int* bsum = blockIdx.x ? bsumV : bsumF;
    const int n = blockIdx.x ? NBV : NBF;
    __shared__ int sh[256];
    const int t = threadIdx.x;
    const int v = (t < n) ? bsum[t] : 0;
    sh[t] = v;
    __syncthreads();
    for (int off = 1; off < 256; off <<= 1) {
        int u = (t >= off) ? sh[t - off] : 0;
        __syncthreads();
        sh[t] += u;
        __syncthreads();
    }
    if (t < n) bsum[t] = sh[t] - v;
}

// phase 3: per-block exclusive scan + block offset -> offs/cur
__global__ __launch_bounds__(256)
void cs3_k(const int* __restrict__ cntF, const int* __restrict__ cntV,
           const int* __restrict__ bsumF, const int* __restrict__ bsumV,
           int* __restrict__ offsF, int* __restrict__ curF,
           int* __restrict__ offsV, int* __restrict__ curV)
{
    __shared__ int sh[256];
    const int b = blockIdx.x;
    const int* cnt; int n; const int* bsum; int bb; int* offs; int* cur;
    if (b < NBF) { cnt = cntF; n = NFAC; bsum = bsumF; bb = b; offs = offsF; cur = curF; }
    else         { cnt = cntV; n = NVAR; bsum = bsumV; bb = b - NBF; offs = offsV; cur = curV; }
    const int t = threadIdx.x;
    const int i = bb * 256 + t;
    const int v = (i < n) ? cnt[i] : 0;
    sh[t] = v;
    __syncthreads();
    for (int off = 1; off < 256; off <<= 1) {
        int u = (t >= off) ? sh[t - off] : 0;
        __syncthreads();
        sh[t] += u;
        __syncthreads();
    }
    const int excl = sh[t] - v + bsum[bb];
    if (i < n) {
        offs[i] = excl; cur[i] = excl;
        if (i == n - 1) offs[n] = excl + v;
    }
}

__global__ __launch_bounds__(256)
void scatter_k(const int* __restrict__ src, const int* __restrict__ dst,
               int* __restrict__ curV, int* __restrict__ curF,
               int* __restrict__ lstV, int* __restrict__ lstF)
{
    int e = blockIdx.x * 256 + threadIdx.x;
    if (e < NEDGE) {
        int s = src[e], d = dst[e];
        int pf = atomicAdd(&curF[d], 1);
        lstF[pf] = s;
        int pv = atomicAdd(&curV[s], 1);
        lstV[pv] = d;
    }
}

// ---------------- gather-aggregate (bf16 in/out, f32 accumulate) ----------------
__global__ __launch_bounds__(256)
void aggb_k(const bf16_t* __restrict__ Pa, const bf16_t* __restrict__ Pb,
            const int* __restrict__ offs, const int* __restrict__ lst,
            bf16_t* __restrict__ agg, int Na)
{
    int a = blockIdx.x * 4 + (threadIdx.x >> 6);
    if (a >= Na) return;
    int lane = threadIdx.x & 63;
    const size_t c = (size_t)lane * 4;
    bf16x4 bv = *(const bf16x4*)(Pa + (size_t)a * DD + c);
    const float b0 = (float)bv[0], b1 = (float)bv[1], b2 = (float)bv[2], b3 = (float)bv[3];
    float s0 = 0.f, s1 = 0.f, s2 = 0.f, s3 = 0.f;
    const int e0 = offs[a], e1 = offs[a + 1];
    for (int e = e0; e < e1; ++e) {
        int b = lst[e];
        bf16x4 x = *(const bf16x4*)(Pb + (size_t)b * DD + c);
        s0 += fmaxf(b0 + (float)x[0], 0.f);
        s1 += fmaxf(b1 + (float)x[1], 0.f);
        s2 += fmaxf(b2 + (float)x[2], 0.f);
        s3 += fmaxf(b3 + (float)x[3], 0.f);
    }
    bf16x4 o;
    o[0] = (bf16_t)s0; o[1] = (bf16_t)s1; o[2] = (bf16_t)s2; o[3] = (bf16_t)s3;
    *(bf16x4*)(agg + (size_t)a * DD + c) = o;
}

// ---------------- global node ----------------
__global__ __launch_bounds__(256)
void gate_k(const float* __restrict__ fac, const float* __restrict__ gw,
            const float* __restrict__ gb, float* __restrict__ gate)
{
    int f = blockIdx.x * 4 + (threadIdx.x >> 6);
    int lane = threadIdx.x & 63;
    float4 x = *(const float4*)(fac + (size_t)f * DD + lane * 4);
    float4 w = *(const float4*)(gw + lane * 4);
    float s = x.x * w.x + x.y * w.y + x.z * w.z + x.w * w.w;
#pragma unroll
    for (int o = 32; o > 0; o >>= 1) s += __shfl_down(s, o);
    if (lane == 0) gate[f] = s + gb[0];
}

__global__ __launch_bounds__(256)
void segsm_k(const float* __restrict__ gate, const int* __restrict__ batch,
             float* __restrict__ mx, float* __restrict__ den)
{
    int g = blockIdx.x;
    int tid = threadIdx.x;
    __shared__ float red[256];
    float m = -1e30f;
    for (int i = tid; i < NFAC; i += 256)
        if (batch[i] == g) m = fmaxf(m, gate[i]);
    red[tid] = m; __syncthreads();
    for (int s = 128; s > 0; s >>= 1) {
        if (tid < s) red[tid] = fmaxf(red[tid], red[tid + s]);
        __syncthreads();
    }
    float gm = red[0]; __syncthreads();
    float sum = 0.f;
    for (int i = tid; i < NFAC; i += 256)
        if (batch[i] == g) sum += __expf(gate[i] - gm);
    red[tid] = sum; __syncthreads();
    for (int s = 128; s > 0; s >>= 1) {
        if (tid < s) red[tid] += red[tid + s];
        __syncthreads();
    }
    if (tid == 0) { mx[g] = gm; den[g] = red[0]; }
}

__global__ __launch_bounds__(256)
void gagg_k(const bf16_t* __restrict__ t, const float* __restrict__ gate,
            const int* __restrict__ batch, const float* __restrict__ mx,
            const float* __restrict__ den, float* __restrict__ gagg)
{
    int tid = threadIdx.x;
    int f0 = blockIdx.x * 64;
    float a = 0.f;
    int cur = batch[f0];
    for (int f = f0; f < f0 + 64; ++f) {
        int b = batch[f];
        if (b != cur) {
            atomicAdd(&gagg[(size_t)cur * DD + tid], a);
            a = 0.f; cur = b;
        }
        float coef = __expf(gate[f] - mx[b]) / den[b];
        a += coef * (float)t[(size_t)f * DD + tid];
    }
    atomicAdd(&gagg[(size_t)cur * DD + tid], a);
}

__global__ __launch_bounds__(256)
void gfin_k(const float* __restrict__ gagg, const float* __restrict__ glW,
            const float* __restrict__ glb, float* __restrict__ gout)
{
    int row = blockIdx.x, col = threadIdx.x;
    float s = glb[col];
    for (int k = 0; k < DD; ++k) s += gagg[row * DD + k] * glW[k * DD + col];
    gout[row * DD + col] = fmaxf(s, 0.f);
}

extern "C" void kernel_launch(void* const* d_in, const int* in_sizes, int n_in,
                              void* d_out, int out_size, void* d_ws, size_t ws_size,
                              hipStream_t stream) {
    (void)in_sizes; (void)n_in; (void)out_size; (void)ws_size;
    const float* variables = (const float*)d_in[0];
    const float* factors   = (const float*)d_in[1];
    const int*   edge_index = (const int*)d_in[3];
    const int*   batch      = (const int*)d_in[4];
    const float* mW_v2f = (const float*)d_in[5];
    const float* mb_v2f = (const float*)d_in[6];
    const float* cW_v2f = (const float*)d_in[7];
    const float* cb_v2f = (const float*)d_in[8];
    const float* mW_f2v = (const float*)d_in[9];
    const float* mb_f2v = (const float*)d_in[10];
    const float* cW_f2v = (const float*)d_in[11];
    const float* cb_f2v = (const float*)d_in[12];
    const float* gate_W = (const float*)d_in[13];
    const float* gate_b = (const float*)d_in[14];
    const float* att_W  = (const float*)d_in[15];
    const float* att_b  = (const float*)d_in[16];
    const float* gl_W   = (const float*)d_in[17];
    const float* gl_b   = (const float*)d_in[18];

    const int* src = edge_index;           // row 0: variable idx
    const int* dst = edge_index + NEDGE;   // row 1: factor idx

    float* out = (float*)d_out;
    float* V1 = out;                                  // final variables (also bf16 P scratch)
    float* F1 = out + (size_t)NVAR * DD;              // final factors (also bf16 P scratch)
    float* gout = out + (size_t)(NVAR + NFAC) * DD;
    bf16_t* V1b = (bf16_t*)V1;
    bf16_t* F1b = (bf16_t*)F1;

    float* ws  = (float*)d_ws;
    float* F0   = ws;                               // NFAC*DD f32 (fac1; also bf16 scratch later)
    float* V0   = F0 + (size_t)NFAC * DD;           // NVAR*DD f32 (var1)
    bf16_t* AGG = (bf16_t*)(V0 + (size_t)NVAR * DD);// NFAC*DD bf16
    float* gate = (float*)(AGG + (size_t)NFAC * DD);// NFAC
    float* mx   = gate + NFAC;                      // NGRAPH
    float* den  = mx + NGRAPH;                      // NGRAPH
    float* gagg = den + NGRAPH;                     // NGRAPH*DD
    int* ip    = (int*)(gagg + (size_t)NGRAPH * DD);
    int* cntF  = ip;              ip += NFAC;
    int* offsF = ip;              ip += NFAC + 1;
    int* curF  = ip;              ip += NFAC;
    int* lstF  = ip;              ip += NEDGE;
    int* cntV  = ip;              ip += NVAR;
    int* offsV = ip;              ip += NVAR + 1;
    int* curV  = ip;              ip += NVAR;
    int* lstV  = ip;              ip += NEDGE;
    int* bsumF = ip;              ip += NBF;
    int* bsumV = ip;              ip += NBV;
    bf16_t* F0b = (bf16_t*)F0;

    // bf16 transposed-weight pool (16B aligned)
    bf16_t* wt = (bf16_t*)(((uintptr_t)ip + 15) & ~(uintptr_t)15);
    bf16_t* WT_mv2f[2]; bf16_t* WT_cv2f[2]; bf16_t* WT_mf2v[2]; bf16_t* WT_cf2v[2];
    size_t woff = 0;
    for (int l = 0; l < 2; ++l) { WT_mv2f[l] = wt + woff; woff += (size_t)DD * 2 * DD; }
    for (int l = 0; l < 2; ++l) { WT_cv2f[l] = wt + woff; woff += (size_t)DD * 2 * DD; }
    for (int l = 0; l < 2; ++l) { WT_mf2v[l] = wt + woff; woff += (size_t)DD * 2 * DD; }
    for (int l = 0; l < 2; ++l) { WT_cf2v[l] = wt + woff; woff += (size_t)DD * 2 * DD; }
    bf16_t* WT_att = wt + woff;

    dim3 blk(256);

    // ---- all 9 weight transposes in one launch
    {
        WtJobs jobs;
        for (int l = 0; l < 2; ++l) {
            jobs.W[l]     = mW_v2f + (size_t)l * 2 * DD * DD; jobs.T[l]     = WT_mv2f[l]; jobs.KK[l]     = 2 * DD;
            jobs.W[2 + l] = cW_v2f + (size_t)l * 2 * DD * DD; jobs.T[2 + l] = WT_cv2f[l]; jobs.KK[2 + l] = 2 * DD;
            jobs.W[4 + l] = mW_f2v + (size_t)l * 2 * DD * DD; jobs.T[4 + l] = WT_mf2v[l]; jobs.KK[4 + l] = 2 * DD;
            jobs.W[6 + l] = cW_f2v + (size_t)l * 2 * DD * DD; jobs.T[6 + l] = WT_cf2v[l]; jobs.KK[6 + l] = 2 * DD;
        }
        jobs.W[8] = att_W; jobs.T[8] = WT_att; jobs.KK[8] = DD;
        wtall_k<<<dim3(2 * DD / 32, DD / 32, 9), blk, 0, stream>>>(jobs);
    }

    // ---- CSR build
    hipMemsetAsync(cntF, 0, NFAC * sizeof(int), stream);
    hipMemsetAsync(cntV, 0, NVAR * sizeof(int), stream);
    count_k<<<dim3((NEDGE + 255) / 256), blk, 0, stream>>>(src, dst, cntV, cntF);
    cs1_k<<<dim3(NBF + NBV), blk, 0, stream>>>(cntF, cntV, bsumF, bsumV);
    cs2_k<<<dim3(2), blk, 0, stream>>>(bsumF, bsumV);
    cs3_k<<<dim3(NBF + NBV), blk, 0, stream>>>(cntF, cntV, bsumF, bsumV, offsF, curF, offsV, curV);
    scatter_k<<<dim3((NEDGE + 255) / 256), blk, 0, stream>>>(src, dst, curV, curF, lstV, lstF);

    dim3 gF2((NFAC + GBM - 1) / GBM, DD / GBN);
    dim3 gV2((NVAR + GBM - 1) / GBM, DD / GBN);

    // ================= layer 0 (reads inputs directly) =================
    {
        const float* mb = mb_v2f;           const float* cb = cb_v2f;
        const float* fb = mb_f2v;           const float* db = cb_f2v;
        // v2f: Pf -> F1b, Pv -> V1b
        mgemm_k<false,false,false,false,true><<<gF2, blk, 0, stream>>>(factors, nullptr, WT_mv2f[0], 2*DD, 0, 0, mb, nullptr, F1b, NFAC);
        mgemm_k<false,false,false,false,true><<<gV2, blk, 0, stream>>>(variables, nullptr, WT_mv2f[0], 2*DD, DD, 0, nullptr, nullptr, V1b, NVAR);
        aggb_k<<<dim3(NFAC / 4), blk, 0, stream>>>(F1b, V1b, offsF, lstF, AGG, NFAC);
        mgemm_k<true,true,false,true,false><<<gF2, blk, 0, stream>>>(factors, AGG, WT_cv2f[0], 2*DD, 0, DD, cb, nullptr, F0, NFAC);
        // f2v: Pv2 -> V1b, Pf2 -> F1b (fac1 lives in F0)
        mgemm_k<false,false,false,false,true><<<gV2, blk, 0, stream>>>(variables, nullptr, WT_mf2v[0], 2*DD, 0, 0, fb, nullptr, V1b, NVAR);
        mgemm_k<false,false,false,false,true><<<gF2, blk, 0, stream>>>(F0, nullptr, WT_mf2v[0], 2*DD, DD, 0, nullptr, nullptr, F1b, NFAC);
        aggb_k<<<dim3(NVAR / 4), blk, 0, stream>>>(V1b, F1b, offsV, lstV, AGG, NVAR);
        mgemm_k<true,true,true,true,false><<<gV2, blk, 0, stream>>>(variables, AGG, WT_cf2v[0], 2*DD, 0, DD, db, variables, V0, NVAR);
    }
    // ================= layer 1 (fac=F0, var=V0 -> finals in d_out) =================
    {
        const float* mb = mb_v2f + DD;      const float* cb = cb_v2f + DD;
        const float* fb = mb_f2v + DD;      const float* db = cb_f2v + DD;
        mgemm_k<false,false,false,false,true><<<gF2, blk, 0, stream>>>(F0, nullptr, WT_mv2f[1], 2*DD, 0, 0, mb, nullptr, F1b, NFAC);
        mgemm_k<false,false,false,false,true><<<gV2, blk, 0, stream>>>(V0, nullptr, WT_mv2f[1], 2*DD, DD, 0, nullptr, nullptr, V1b, NVAR);
        aggb_k<<<dim3(NFAC / 4), blk, 0, stream>>>(F1b, V1b, offsF, lstF, AGG, NFAC);
        mgemm_k<true,true,false,true,false><<<gF2, blk, 0, stream>>>(F0, AGG, WT_cv2f[1], 2*DD, 0, DD, cb, nullptr, F1, NFAC);   // fac2 -> d_out
        mgemm_k<false,false,false,false,true><<<gV2, blk, 0, stream>>>(V0, nullptr, WT_mf2v[1], 2*DD, 0, 0, fb, nullptr, V1b, NVAR);
        mgemm_k<false,false,false,false,true><<<gF2, blk, 0, stream>>>(F1, nullptr, WT_mf2v[1], 2*DD, DD, 0, nullptr, nullptr, F0b, NFAC); // F0 (fac1) dead
        aggb_k<<<dim3(NVAR / 4), blk, 0, stream>>>(V1b, F0b, offsV, lstV, AGG, NVAR);
        mgemm_k<true,true,true,true,false><<<gV2, blk, 0, stream>>>(V0, AGG, WT_cf2v[1], 2*DD, 0, DD, db, V0, V1, NVAR);          // var2 -> d_out
    }

    // ================= global node =================
    gate_k<<<dim3(NFAC / 4), blk, 0, stream>>>(F1, gate_W, gate_b, gate);
    segsm_k<<<dim3(NGRAPH), blk, 0, stream>>>(gate, batch, mx, den);
    mgemm_k<false,false,false,false,true><<<gF2, blk, 0, stream>>>(F1, nullptr, WT_att, DD, 0, 0, att_b, nullptr, F0b, NFAC);
    hipMemsetAsync(gagg, 0, (size_t)NGRAPH * DD * sizeof(float), stream);
    gagg_k<<<dim3(NFAC / 64), blk, 0, stream>>>(F0b, gate, batch, mx, den, gagg);
    gfin_k<<<dim3(NGRAPH), blk, 0, stream>>>(gagg, gl_W, gl_b, gout);
}